// Round 8
// baseline (461.992 us; speedup 1.0000x reference)
//
#include <hip/hip_runtime.h>

// PromptPool: B=32768 rows, D=1024, P=20 prompts, K=5 rounds.
// Phase split:
//   pp_pre     - normalize keys, VK/VV cross-dot tables
//   pp_dots    - per row: self dot + 20 key dots (f64, keys in LDS) + 20 val
//                dots (f32, vals from L2). One input pass. Loops `unroll 1`
//                (R6: bounded sched window -> no spills) + 1-deep fragment
//                prefetch (R8: hide DS/L2 latency under the FMA+butterfly chain).
//   pp_decide  - one LANE per row: K=5 analytic softmax/argmax loop
//   pp_wsumloss- fused: per-wave f64 commitment grouping (stride 2048) + final
//                reduction, identical summation tree to the old two kernels.
//   pp_bcast   - pure broadcast: out_sel[row,t] = vals[idx[row,t]]
//
// R8: R7's fusion was a wash (387 us flat): unroll-1 loops stalled on each
// iteration's loads (no overlap). Fix = prefetch next fragment before the
// current FMA/butterfly chain; chains are ~280 cy, covering L2 (~250) and
// DS (~120) latency. +32 transient regs, peak ~110 < 128.

#define D  1024
#define PP 20
#define SBS 44                 // sbuf row stride in floats (41 used, 16B-aligned)
#define NBK 512                // blocks for dots kernel (2 per CU, 80 KiB LDS)
#define TBK 512                // threads per block = 8 waves
#define NWK (NBK * (TBK / 64)) // 4096 waves, 8 rows each
#define NWSUM 2048             // commitment-sum grouping (original kernel's order)

// ---------------- kernel 1: precompute norm_keys, VK, VV ----------------
__global__ __launch_bounds__(1024) void pp_pre(
    const float* __restrict__ keys,
    const float* __restrict__ vals,
    float* __restrict__ nk,     // ws: normalized keys f32 [PP*D]
    float* __restrict__ vkf,    // ws: VK = v_q . k_norm_p, f32 [PP*PP]
    float* __restrict__ vvf)    // ws: VV = v_q . v_p,      f32 [PP*PP]
{
    __shared__ float nk_s[PP * D];
    __shared__ float nrm_s[PP];
    const int tid = threadIdx.x;

    if (tid < PP) {
        const float* kp = keys + tid * D;
        double s0 = 0.0, s1 = 0.0;
        for (int d = 0; d < D; d += 2) {
            s0 += (double)kp[d]     * (double)kp[d];
            s1 += (double)kp[d + 1] * (double)kp[d + 1];
        }
        nrm_s[tid] = sqrtf((float)(s0 + s1));
    }
    __syncthreads();

    for (int i = tid; i < PP * D; i += blockDim.x) {
        float x = keys[i] / nrm_s[i >> 10];
        nk_s[i] = x;
        nk[i]   = x;
    }
    __syncthreads();

    if (tid < 2 * PP * PP) {
        const int which = tid & 1;              // 0 -> VK, 1 -> VV
        const int rem   = tid >> 1;             // q*PP + p
        const int q = rem / PP, p = rem % PP;
        const float* vq    = vals + q * D;
        const float* other = which ? (vals + p * D) : (nk_s + p * D);
        double s0 = 0.0, s1 = 0.0;
        for (int d = 0; d < D; d += 2) {
            s0 += (double)vq[d]     * (double)other[d];
            s1 += (double)vq[d + 1] * (double)other[d + 1];
        }
        float r = (float)(s0 + s1);
        if (which) vvf[rem] = r; else vkf[rem] = r;
    }
}

// ------- kernel 2: all 41 dots per row (keys via LDS, vals via L2) ----------
__global__ __launch_bounds__(TBK) void pp_dots(
    const float* __restrict__ input,
    const float* __restrict__ vals,
    const float* __restrict__ nk,
    float* __restrict__ sbuf,   // [B][SBS]: 0..19 -> s, 20..39 -> rvp, 40 -> ||x||^2
    int B)
{
    __shared__ float s_keys[PP * D];   // 80 KiB -> 2 blocks/CU
    const int tid = threadIdx.x;
    {
        const float4* a = (const float4*)nk;
        float4* sa = (float4*)s_keys;
        for (int i = tid; i < PP * D / 4; i += TBK) sa[i] = a[i];
    }
    __syncthreads();

    const int lane = tid & 63;
    const int gw   = blockIdx.x * (TBK / 64) + (tid >> 6);

    int row = gw;
    if (row >= B) return;

    const float4* ip0 = (const float4*)(input + (size_t)row * D);
    float4 r0 = ip0[lane], r1 = ip0[lane + 64], r2 = ip0[lane + 128], r3 = ip0[lane + 192];

    while (row < B) {
        const int nrow = row + NWK;
        float4 n0 = r0, n1 = r1, n2 = r2, n3 = r3;
        if (nrow < B) {   // prefetch next row
            const float4* np = (const float4*)(input + (size_t)nrow * D);
            n0 = np[lane]; n1 = np[lane + 64]; n2 = np[lane + 128]; n3 = np[lane + 192];
        }

        float rv[16] = { r0.x,r0.y,r0.z,r0.w, r1.x,r1.y,r1.z,r1.w,
                         r2.x,r2.y,r2.z,r2.w, r3.x,r3.y,r3.z,r3.w };
        double rd[16];
#pragma unroll
        for (int i = 0; i < 16; i++) rd[i] = (double)rv[i];   // exact cvt, once

        // self dot (||input||^2), f32 chain as original, reduce immediately
        float sq = 0.f;
#pragma unroll
        for (int i = 0; i < 16; i++) sq = fmaf(rv[i], rv[i], sq);
#pragma unroll
        for (int m = 1; m < 64; m <<= 1) sq += __shfl_xor(sq, m, 64);

        float o = sq;   // lane 40 keeps this; lanes 0..39 overwritten below

        // ---- key dots: f64 chains, keys from LDS, 1-deep ds_read prefetch ---
        {
            const float4* kp0 = (const float4*)(s_keys);
            float4 k0 = kp0[lane], k1 = kp0[lane + 64], k2 = kp0[lane + 128], k3 = kp0[lane + 192];
#pragma unroll 1
            for (int p = 0; p < PP; p++) {   // NOT unrolled (R6: no spills)
                float kk[16] = { k0.x,k0.y,k0.z,k0.w, k1.x,k1.y,k1.z,k1.w,
                                 k2.x,k2.y,k2.z,k2.w, k3.x,k3.y,k3.z,k3.w };
                const int pn = (p + 1 < PP) ? p + 1 : p;   // uniform; last = redundant
                const float4* kp = (const float4*)(s_keys + pn * D);
                k0 = kp[lane]; k1 = kp[lane + 64]; k2 = kp[lane + 128]; k3 = kp[lane + 192];

                double acc = 0.0;
#pragma unroll
                for (int i = 0; i < 16; i++)
                    acc = fma(rd[i], (double)kk[i], acc);     // same chain order
                float sp = (float)acc;
#pragma unroll
                for (int m = 1; m < 64; m <<= 1) sp += __shfl_xor(sp, m, 64);
                o = (lane == p) ? sp : o;
            }
        }

        // ---- val dots: f32 chains, vals from L2, 1-deep load prefetch ----
        {
            const float4* vp0 = (const float4*)(vals);
            float4 v0 = vp0[lane], v1 = vp0[lane + 64], v2 = vp0[lane + 128], v3 = vp0[lane + 192];
#pragma unroll 1
            for (int p = 0; p < PP; p++) {   // NOT unrolled
                float vl[16] = { v0.x,v0.y,v0.z,v0.w, v1.x,v1.y,v1.z,v1.w,
                                 v2.x,v2.y,v2.z,v2.w, v3.x,v3.y,v3.z,v3.w };
                const int pn = (p + 1 < PP) ? p + 1 : p;
                const float4* vp = (const float4*)(vals + (size_t)pn * D);
                v0 = vp[lane]; v1 = vp[lane + 64]; v2 = vp[lane + 128]; v3 = vp[lane + 192];

                float ab = 0.f;
#pragma unroll
                for (int i = 0; i < 16; i++) ab = fmaf(rv[i], vl[i], ab);
#pragma unroll
                for (int m = 1; m < 64; m <<= 1) ab += __shfl_xor(ab, m, 64);
                o = (lane == PP + p) ? ab : o;
            }
        }

        if (lane < 2 * PP + 1) sbuf[(size_t)row * SBS + lane] = o;  // 164B/row

        r0 = n0; r1 = n1; r2 = n2; r3 = n3;
        row = nrow;
    }
}

// ---------------- kernel 3: decide (1 LANE per row) ----------------
__global__ __launch_bounds__(256) void pp_decide(
    const float* __restrict__ sbuf,   // [B][SBS]
    const float* __restrict__ vkf,
    const float* __restrict__ vvf,
    float* __restrict__ out_idx,      // [B*K] as float
    float* __restrict__ cmrow,        // [B] per-row commitment (f32, exact values)
    int B, int K)
{
    __shared__ float vk_s[PP * PP];
    __shared__ float vv_s[PP * PP];
    for (int i = threadIdx.x; i < PP * PP; i += 256) { vk_s[i] = vkf[i]; vv_s[i] = vvf[i]; }
    __syncthreads();
    const int row = blockIdx.x * 256 + threadIdx.x;
    if (row >= B) return;

    const float4* rp = (const float4*)(sbuf + (size_t)row * SBS);
    float s[PP], rvp[PP];
    {
        float4 a0 = rp[0], a1 = rp[1], a2 = rp[2], a3 = rp[3], a4 = rp[4];
        float4 b0 = rp[5], b1 = rp[6], b2 = rp[7], b3 = rp[8], b4 = rp[9];
        s[0]=a0.x;  s[1]=a0.y;  s[2]=a0.z;  s[3]=a0.w;
        s[4]=a1.x;  s[5]=a1.y;  s[6]=a1.z;  s[7]=a1.w;
        s[8]=a2.x;  s[9]=a2.y;  s[10]=a2.z; s[11]=a2.w;
        s[12]=a3.x; s[13]=a3.y; s[14]=a3.z; s[15]=a3.w;
        s[16]=a4.x; s[17]=a4.y; s[18]=a4.z; s[19]=a4.w;
        rvp[0]=b0.x;  rvp[1]=b0.y;  rvp[2]=b0.z;  rvp[3]=b0.w;
        rvp[4]=b1.x;  rvp[5]=b1.y;  rvp[6]=b1.z;  rvp[7]=b1.w;
        rvp[8]=b2.x;  rvp[9]=b2.y;  rvp[10]=b2.z; rvp[11]=b2.w;
        rvp[12]=b3.x; rvp[13]=b3.y; rvp[14]=b3.z; rvp[15]=b3.w;
        rvp[16]=b4.x; rvp[17]=b4.y; rvp[18]=b4.z; rvp[19]=b4.w;
    }
    float rn2 = ((const float*)rp)[2 * PP];

    float cm = 0.f;
    for (int t = 0; t < K; t++) {
        float nrm = sqrtf(rn2);
        float sims[PP];
#pragma unroll
        for (int p = 0; p < PP; p++) sims[p] = s[p] / nrm;
        float mx = sims[0];
#pragma unroll
        for (int p = 1; p < PP; p++) mx = fmaxf(mx, sims[p]);
        float e[PP];
        float denom = 0.f;
#pragma unroll
        for (int p = 0; p < PP; p++) { e[p] = expf(sims[p] - mx); denom += e[p]; }
        float best = -1.f; int bi = 0;
#pragma unroll
        for (int p = 0; p < PP; p++) {
            float pr = e[p] / denom;
            if (pr > best) { best = pr; bi = p; }
        }
        cm += best;
        out_idx[(size_t)row * K + t] = (float)bi;

        if (t + 1 < K) {
            float rvbi = rvp[0];
#pragma unroll
            for (int p = 1; p < PP; p++) rvbi = (p == bi) ? rvp[p] : rvbi;
            rn2 = rn2 - 2.f * rvbi + vv_s[bi * PP + bi];
#pragma unroll
            for (int p = 0; p < PP; p++) { s[p] -= vk_s[bi * PP + p]; rvp[p] -= vv_s[bi * PP + p]; }
        }
    }
    cmrow[row] = cm;
}

// ------- kernel 4: fused wsum+loss (identical two-level f64 tree) -----------
__global__ __launch_bounds__(256) void pp_wsumloss(
    const float* __restrict__ cmrow, float* __restrict__ out_loss, int B)
{
    __shared__ double sh[4];
    const int tid = threadIdx.x;
    double s = 0.0;
    // j ascending == old loss's i = tid + 256*j read order; each w is the old
    // wsum[g] inner sum (r = g, g+2048, ... ascending). Same trees -> same bits.
    for (int j = 0; j < NWSUM / 256; j++) {
        const int g = tid + 256 * j;
        double w = 0.0;
        for (int r = g; r < B; r += NWSUM) w += (double)cmrow[r];
        s += w;
    }
#pragma unroll
    for (int m = 1; m < 64; m <<= 1) s += __shfl_xor(s, m, 64);
    if ((tid & 63) == 0) sh[tid >> 6] = s;
    __syncthreads();
    if (tid == 0) {
        double tot = sh[0] + sh[1] + sh[2] + sh[3];
        out_loss[0] = (float)(-(tot / (double)B));
    }
}

// ---------------- kernel 5: broadcast writer (wave per (row,t) task) ---------
__global__ __launch_bounds__(256) void pp_bcast(
    const float* __restrict__ vals,
    const float* __restrict__ out_idx,
    float* __restrict__ out_sel,
    int nTask)
{
    const int lane = threadIdx.x & 63;
    const int wid  = blockIdx.x * 4 + (threadIdx.x >> 6);
    const int nw   = gridDim.x * 4;

    int task = wid;
    int bi = (task < nTask) ? (int)out_idx[task] : 0;
    while (task < nTask) {
        const int ntask = task + nw;
        const int nbi = (ntask < nTask) ? (int)out_idx[ntask] : 0;  // prefetch idx

        const float4* pv = (const float4*)(vals + (size_t)bi * D);
        float4* ob = (float4*)(out_sel + (size_t)task * D);
        float4 a = pv[lane], b = pv[lane + 64], c = pv[lane + 128], d = pv[lane + 192];
        ob[lane]       = a;
        ob[lane + 64]  = b;
        ob[lane + 128] = c;
        ob[lane + 192] = d;

        task = ntask; bi = nbi;
    }
}

extern "C" void kernel_launch(void* const* d_in, const int* in_sizes, int n_in,
                              void* d_out, int out_size, void* d_ws, size_t ws_size,
                              hipStream_t stream) {
    const float* input = (const float*)d_in[0];
    const float* keys  = (const float*)d_in[1];
    const float* vals  = (const float*)d_in[2];

    const int B = in_sizes[0] / D;                       // 32768
    const int K = (out_size - 1) / (B * (D + 1));        // 5

    float* out_sel  = (float*)d_out;
    const size_t selN = (size_t)B * K * D;
    float* out_loss = out_sel + selN;
    float* out_idx  = out_sel + selN + 1;

    char*  ws    = (char*)d_ws;
    float* nk    = (float*)ws;                           // PP*D f32 = 81920 B
    float* vkf   = nk + PP * D;                          // 400 f32
    float* vvf   = vkf + PP * PP;                        // 400 f32

    // Large scratch lives INSIDE out_sel (regenerated in full by pp_bcast later):
    //   sbuf = [B][SBS] f32 (5.8 MB), cmrow = [B] f32 (128 KB) — far below selN.
    float* sbuf  = out_sel;
    float* cmrow = out_sel + (size_t)B * SBS;

    const int nTask = B * K;

    pp_pre     <<<1, 1024, 0, stream>>>(keys, vals, nk, vkf, vvf);
    pp_dots    <<<NBK, TBK, 0, stream>>>(input, vals, nk, sbuf, B);
    pp_decide  <<<(B + 255) / 256, 256, 0, stream>>>(sbuf, vkf, vvf, out_idx, cmrow, B, K);
    pp_wsumloss<<<1, 256, 0, stream>>>(cmrow, out_loss, B);
    pp_bcast   <<<2048, 256, 0, stream>>>(vals, out_idx, out_sel, nTask);
}

// Round 9
// 377.998 us; speedup vs baseline: 1.2222x; 1.2222x over previous
//
#include <hip/hip_runtime.h>

// PromptPool: B=32768 rows, D=1024, P=20 prompts, K=5 rounds.
// Phase split:
//   pp_pre    - normalize keys, VK/VV cross-dot tables
//   pp_dots   - PAIR of rows per wave iteration: self dots + per-row key dots
//               (f64, keys in 80 KiB LDS, verbatim R7 loop) + val dots with
//               SHARED fragments (one L2 load feeds both rows' f32 chains).
//               All loops `unroll 1` (R6), no cross-iteration register
//               rotation (R8 lesson: rotation costs movs under unroll 1).
//   pp_decide - one LANE per row: K=5 analytic softmax/argmax loop
//   pp_wsum   - original per-wave f64 commitment grouping (stride 2048)
//   pp_bcast  - pure broadcast: out_sel[row,t] = vals[idx[row,t]]
//   pp_loss   - final reduction
//
// R9: R8's prefetch regressed (+75 us: rotation movs + fused single-block
// wsumloss latency chain). Revert both. New lever: pair-row val-fragment
// sharing — halves val L2 traffic and hides L2 latency under two independent
// chains, with peak live regs ~95 (rd arrays scoped per key loop).

#define D  1024
#define PP 20
#define SBS 44                 // sbuf row stride in floats (41 used, 16B-aligned)
#define NBK 512                // blocks for dots kernel (2 per CU, 80 KiB LDS)
#define TBK 512                // threads per block = 8 waves
#define NWK (NBK * (TBK / 64)) // 4096 waves, 8 rows each (4 pairs)
#define NWSUM 2048             // commitment-sum grouping (original kernel's order)

// ---------------- kernel 1: precompute norm_keys, VK, VV ----------------
__global__ __launch_bounds__(1024) void pp_pre(
    const float* __restrict__ keys,
    const float* __restrict__ vals,
    float* __restrict__ nk,     // ws: normalized keys f32 [PP*D]
    float* __restrict__ vkf,    // ws: VK = v_q . k_norm_p, f32 [PP*PP]
    float* __restrict__ vvf)    // ws: VV = v_q . v_p,      f32 [PP*PP]
{
    __shared__ float nk_s[PP * D];
    __shared__ float nrm_s[PP];
    const int tid = threadIdx.x;

    if (tid < PP) {
        const float* kp = keys + tid * D;
        double s0 = 0.0, s1 = 0.0;
        for (int d = 0; d < D; d += 2) {
            s0 += (double)kp[d]     * (double)kp[d];
            s1 += (double)kp[d + 1] * (double)kp[d + 1];
        }
        nrm_s[tid] = sqrtf((float)(s0 + s1));
    }
    __syncthreads();

    for (int i = tid; i < PP * D; i += blockDim.x) {
        float x = keys[i] / nrm_s[i >> 10];
        nk_s[i] = x;
        nk[i]   = x;
    }
    __syncthreads();

    if (tid < 2 * PP * PP) {
        const int which = tid & 1;              // 0 -> VK, 1 -> VV
        const int rem   = tid >> 1;             // q*PP + p
        const int q = rem / PP, p = rem % PP;
        const float* vq    = vals + q * D;
        const float* other = which ? (vals + p * D) : (nk_s + p * D);
        double s0 = 0.0, s1 = 0.0;
        for (int d = 0; d < D; d += 2) {
            s0 += (double)vq[d]     * (double)other[d];
            s1 += (double)vq[d + 1] * (double)other[d + 1];
        }
        float r = (float)(s0 + s1);
        if (which) vvf[rem] = r; else vkf[rem] = r;
    }
}

// ------- kernel 2: all 41 dots, PAIR of rows per iteration ------------------
__global__ __launch_bounds__(TBK) void pp_dots(
    const float* __restrict__ input,
    const float* __restrict__ vals,
    const float* __restrict__ nk,
    float* __restrict__ sbuf,   // [B][SBS]: 0..19 -> s, 20..39 -> rvp, 40 -> ||x||^2
    int B)
{
    __shared__ float s_keys[PP * D];   // 80 KiB -> 2 blocks/CU
    const int tid = threadIdx.x;
    {
        const float4* a = (const float4*)nk;
        float4* sa = (float4*)s_keys;
        for (int i = tid; i < PP * D / 4; i += TBK) sa[i] = a[i];
    }
    __syncthreads();

    const int lane = tid & 63;
    const int gw   = blockIdx.x * (TBK / 64) + (tid >> 6);

    for (int rowA = gw; rowA < B; rowA += 2 * NWK) {
        const int  rowB = rowA + NWK;
        const bool hasB = rowB < B;

        // load both rows (B falls back to A's data when absent; not written)
        const float4* ipA = (const float4*)(input + (size_t)rowA * D);
        float4 a0 = ipA[lane], a1 = ipA[lane + 64], a2 = ipA[lane + 128], a3 = ipA[lane + 192];
        const float4* ipB = (const float4*)(input + (size_t)(hasB ? rowB : rowA) * D);
        float4 b0 = ipB[lane], b1 = ipB[lane + 64], b2 = ipB[lane + 128], b3 = ipB[lane + 192];

        float rvA[16] = { a0.x,a0.y,a0.z,a0.w, a1.x,a1.y,a1.z,a1.w,
                          a2.x,a2.y,a2.z,a2.w, a3.x,a3.y,a3.z,a3.w };
        float rvB[16] = { b0.x,b0.y,b0.z,b0.w, b1.x,b1.y,b1.z,b1.w,
                          b2.x,b2.y,b2.z,b2.w, b3.x,b3.y,b3.z,b3.w };

        // self dots (f32 chains as original, reduce immediately)
        float sqA = 0.f;
#pragma unroll
        for (int i = 0; i < 16; i++) sqA = fmaf(rvA[i], rvA[i], sqA);
#pragma unroll
        for (int m = 1; m < 64; m <<= 1) sqA += __shfl_xor(sqA, m, 64);
        float sqB = 0.f;
#pragma unroll
        for (int i = 0; i < 16; i++) sqB = fmaf(rvB[i], rvB[i], sqB);
#pragma unroll
        for (int m = 1; m < 64; m <<= 1) sqB += __shfl_xor(sqB, m, 64);

        float oA = sqA, oB = sqB;   // lane 40 keeps these

        // ---- key dots row A: f64 chains, keys from LDS (verbatim R7 loop) --
        {
            double rd[16];
#pragma unroll
            for (int i = 0; i < 16; i++) rd[i] = (double)rvA[i];
#pragma unroll 1
            for (int p = 0; p < PP; p++) {
                const float4* kp = (const float4*)(s_keys + p * D);
                float4 k0 = kp[lane], k1 = kp[lane + 64], k2 = kp[lane + 128], k3 = kp[lane + 192];
                float kk[16] = { k0.x,k0.y,k0.z,k0.w, k1.x,k1.y,k1.z,k1.w,
                                 k2.x,k2.y,k2.z,k2.w, k3.x,k3.y,k3.z,k3.w };
                double acc = 0.0;
#pragma unroll
                for (int i = 0; i < 16; i++) acc = fma(rd[i], (double)kk[i], acc);
                float sp = (float)acc;
#pragma unroll
                for (int m = 1; m < 64; m <<= 1) sp += __shfl_xor(sp, m, 64);
                oA = (lane == p) ? sp : oA;
            }
        }
        // ---- key dots row B (rd of A is dead; no f64 arrays coexist) ----
        {
            double rd[16];
#pragma unroll
            for (int i = 0; i < 16; i++) rd[i] = (double)rvB[i];
#pragma unroll 1
            for (int p = 0; p < PP; p++) {
                const float4* kp = (const float4*)(s_keys + p * D);
                float4 k0 = kp[lane], k1 = kp[lane + 64], k2 = kp[lane + 128], k3 = kp[lane + 192];
                float kk[16] = { k0.x,k0.y,k0.z,k0.w, k1.x,k1.y,k1.z,k1.w,
                                 k2.x,k2.y,k2.z,k2.w, k3.x,k3.y,k3.z,k3.w };
                double acc = 0.0;
#pragma unroll
                for (int i = 0; i < 16; i++) acc = fma(rd[i], (double)kk[i], acc);
                float sp = (float)acc;
#pragma unroll
                for (int m = 1; m < 64; m <<= 1) sp += __shfl_xor(sp, m, 64);
                oB = (lane == p) ? sp : oB;
            }
        }

        // ---- val dots: ONE fragment load feeds BOTH rows' f32 chains ----
#pragma unroll 1
        for (int p = 0; p < PP; p++) {
            const float4* vp = (const float4*)(vals + (size_t)p * D);
            float4 v0 = vp[lane], v1 = vp[lane + 64], v2 = vp[lane + 128], v3 = vp[lane + 192];
            float vl[16] = { v0.x,v0.y,v0.z,v0.w, v1.x,v1.y,v1.z,v1.w,
                             v2.x,v2.y,v2.z,v2.w, v3.x,v3.y,v3.z,v3.w };
            float abA = 0.f, abB = 0.f;
#pragma unroll
            for (int i = 0; i < 16; i++) abA = fmaf(rvA[i], vl[i], abA);
#pragma unroll
            for (int i = 0; i < 16; i++) abB = fmaf(rvB[i], vl[i], abB);
#pragma unroll
            for (int m = 1; m < 64; m <<= 1) {
                abA += __shfl_xor(abA, m, 64);
                abB += __shfl_xor(abB, m, 64);
            }
            oA = (lane == PP + p) ? abA : oA;
            oB = (lane == PP + p) ? abB : oB;
        }

        if (lane < 2 * PP + 1) {
            sbuf[(size_t)rowA * SBS + lane] = oA;
            if (hasB) sbuf[(size_t)rowB * SBS + lane] = oB;
        }
    }
}

// ---------------- kernel 3: decide (1 LANE per row) ----------------
__global__ __launch_bounds__(256) void pp_decide(
    const float* __restrict__ sbuf,   // [B][SBS]
    const float* __restrict__ vkf,
    const float* __restrict__ vvf,
    float* __restrict__ out_idx,      // [B*K] as float
    float* __restrict__ cmrow,        // [B] per-row commitment (f32, exact values)
    int B, int K)
{
    __shared__ float vk_s[PP * PP];
    __shared__ float vv_s[PP * PP];
    for (int i = threadIdx.x; i < PP * PP; i += 256) { vk_s[i] = vkf[i]; vv_s[i] = vvf[i]; }
    __syncthreads();
    const int row = blockIdx.x * 256 + threadIdx.x;
    if (row >= B) return;

    const float4* rp = (const float4*)(sbuf + (size_t)row * SBS);
    float s[PP], rvp[PP];
    {
        float4 a0 = rp[0], a1 = rp[1], a2 = rp[2], a3 = rp[3], a4 = rp[4];
        float4 b0 = rp[5], b1 = rp[6], b2 = rp[7], b3 = rp[8], b4 = rp[9];
        s[0]=a0.x;  s[1]=a0.y;  s[2]=a0.z;  s[3]=a0.w;
        s[4]=a1.x;  s[5]=a1.y;  s[6]=a1.z;  s[7]=a1.w;
        s[8]=a2.x;  s[9]=a2.y;  s[10]=a2.z; s[11]=a2.w;
        s[12]=a3.x; s[13]=a3.y; s[14]=a3.z; s[15]=a3.w;
        s[16]=a4.x; s[17]=a4.y; s[18]=a4.z; s[19]=a4.w;
        rvp[0]=b0.x;  rvp[1]=b0.y;  rvp[2]=b0.z;  rvp[3]=b0.w;
        rvp[4]=b1.x;  rvp[5]=b1.y;  rvp[6]=b1.z;  rvp[7]=b1.w;
        rvp[8]=b2.x;  rvp[9]=b2.y;  rvp[10]=b2.z; rvp[11]=b2.w;
        rvp[12]=b3.x; rvp[13]=b3.y; rvp[14]=b3.z; rvp[15]=b3.w;
        rvp[16]=b4.x; rvp[17]=b4.y; rvp[18]=b4.z; rvp[19]=b4.w;
    }
    float rn2 = ((const float*)rp)[2 * PP];

    float cm = 0.f;
    for (int t = 0; t < K; t++) {
        float nrm = sqrtf(rn2);
        float sims[PP];
#pragma unroll
        for (int p = 0; p < PP; p++) sims[p] = s[p] / nrm;
        float mx = sims[0];
#pragma unroll
        for (int p = 1; p < PP; p++) mx = fmaxf(mx, sims[p]);
        float e[PP];
        float denom = 0.f;
#pragma unroll
        for (int p = 0; p < PP; p++) { e[p] = expf(sims[p] - mx); denom += e[p]; }
        float best = -1.f; int bi = 0;
#pragma unroll
        for (int p = 0; p < PP; p++) {
            float pr = e[p] / denom;
            if (pr > best) { best = pr; bi = p; }
        }
        cm += best;
        out_idx[(size_t)row * K + t] = (float)bi;

        if (t + 1 < K) {
            float rvbi = rvp[0];
#pragma unroll
            for (int p = 1; p < PP; p++) rvbi = (p == bi) ? rvp[p] : rvbi;
            rn2 = rn2 - 2.f * rvbi + vv_s[bi * PP + bi];
#pragma unroll
            for (int p = 0; p < PP; p++) { s[p] -= vk_s[bi * PP + p]; rvp[p] -= vv_s[bi * PP + p]; }
        }
    }
    cmrow[row] = cm;
}

// ---------------- kernel 4: wsum (original per-wave f64 sum order) ----------
__global__ __launch_bounds__(256) void pp_wsum(
    const float* __restrict__ cmrow, double* __restrict__ wsum, int B)
{
    const int g = blockIdx.x * 256 + threadIdx.x;   // 0..NWSUM-1
    if (g >= NWSUM) return;
    double s = 0.0;
    for (int r = g; r < B; r += NWSUM) s += (double)cmrow[r];  // same order as old csum
    wsum[g] = s;
}

// ---------------- kernel 5: broadcast writer (wave per (row,t) task) ---------
__global__ __launch_bounds__(256) void pp_bcast(
    const float* __restrict__ vals,
    const float* __restrict__ out_idx,
    float* __restrict__ out_sel,
    int nTask)
{
    const int lane = threadIdx.x & 63;
    const int wid  = blockIdx.x * 4 + (threadIdx.x >> 6);
    const int nw   = gridDim.x * 4;

    int task = wid;
    int bi = (task < nTask) ? (int)out_idx[task] : 0;
    while (task < nTask) {
        const int ntask = task + nw;
        const int nbi = (ntask < nTask) ? (int)out_idx[ntask] : 0;  // prefetch idx

        const float4* pv = (const float4*)(vals + (size_t)bi * D);
        float4* ob = (float4*)(out_sel + (size_t)task * D);
        float4 a = pv[lane], b = pv[lane + 64], c = pv[lane + 128], d = pv[lane + 192];
        ob[lane]       = a;
        ob[lane + 64]  = b;
        ob[lane + 128] = c;
        ob[lane + 192] = d;

        task = ntask; bi = nbi;
    }
}

// ---------------- kernel 6: loss reduce ----------------
__global__ __launch_bounds__(256) void pp_loss(
    const double* __restrict__ wsum, float* __restrict__ out_loss, int B)
{
    __shared__ double sh[4];
    const int tid = threadIdx.x;
    double s = 0.0;
    for (int i = tid; i < NWSUM; i += 256) s += wsum[i];
#pragma unroll
    for (int m = 1; m < 64; m <<= 1) s += __shfl_xor(s, m, 64);
    if ((tid & 63) == 0) sh[tid >> 6] = s;
    __syncthreads();
    if (tid == 0) {
        double tot = sh[0] + sh[1] + sh[2] + sh[3];
        out_loss[0] = (float)(-(tot / (double)B));
    }
}

extern "C" void kernel_launch(void* const* d_in, const int* in_sizes, int n_in,
                              void* d_out, int out_size, void* d_ws, size_t ws_size,
                              hipStream_t stream) {
    const float* input = (const float*)d_in[0];
    const float* keys  = (const float*)d_in[1];
    const float* vals  = (const float*)d_in[2];

    const int B = in_sizes[0] / D;                       // 32768
    const int K = (out_size - 1) / (B * (D + 1));        // 5

    float* out_sel  = (float*)d_out;
    const size_t selN = (size_t)B * K * D;
    float* out_loss = out_sel + selN;
    float* out_idx  = out_sel + selN + 1;

    char*  ws    = (char*)d_ws;
    float* nk    = (float*)ws;                           // PP*D f32 = 81920 B
    float* vkf   = nk + PP * D;                          // 400 f32
    float* vvf   = vkf + PP * PP;                        // 400 f32
    double* wsum = (double*)(ws + ((PP * D + 2 * PP * PP) * 4)); // 8-aligned

    // Large scratch lives INSIDE out_sel (regenerated in full by pp_bcast later):
    //   sbuf = [B][SBS] f32 (5.8 MB), cmrow = [B] f32 (128 KB) — far below selN.
    float* sbuf  = out_sel;
    float* cmrow = out_sel + (size_t)B * SBS;

    const int nTask = B * K;

    pp_pre   <<<1, 1024, 0, stream>>>(keys, vals, nk, vkf, vvf);
    pp_dots  <<<NBK, TBK, 0, stream>>>(input, vals, nk, sbuf, B);
    pp_decide<<<(B + 255) / 256, 256, 0, stream>>>(sbuf, vkf, vvf, out_idx, cmrow, B, K);
    pp_wsum  <<<(NWSUM + 255) / 256, 256, 0, stream>>>(cmrow, wsum, B);
    pp_bcast <<<2048, 256, 0, stream>>>(vals, out_idx, out_sel, nTask);
    pp_loss  <<<1, 256, 0, stream>>>(wsum, out_loss, B);
}

// Round 10
// 345.357 us; speedup vs baseline: 1.3377x; 1.0945x over previous
//
#include <hip/hip_runtime.h>

// PromptPool: B=32768 rows, D=1024, P=20 prompts, K=5 rounds.
// Phase split:
//   pp_pre    - normalize keys, VK/VV cross-dot tables
//   pp_dots   - PAIR of rows per iteration. Order: self dots -> val dots
//               (shared val fragment feeds both rows) -> cvt rv->rd (rv dies)
//               -> key dots (ONE ds_read fragment feeds both rows' f64 chains).
//               All p-loops `unroll 1` (R6). Butterfly stages 1,2 use DPP
//               quad_perm (VALU) instead of ds_swizzle (LDS pipe) — same adds,
//               same order, bit-identical.
//   pp_decide - one LANE per row: K=5 analytic softmax/argmax loop
//   pp_wsum   - original per-wave f64 commitment grouping (stride 2048)
//   pp_bcast  - pure broadcast: out_sel[row,t] = vals[idx[row,t]]
//   pp_loss   - final reduction
//
// R10: dots was LDS-pipe-bound (~100 us/CU: 160 key ds_reads/pair + 492
// butterfly swizzles/pair). Key-fragment sharing halves key ds_reads; DPP
// xor1/xor2 moves 1/3 of butterfly stages to the VALU pipe.

#define D  1024
#define PP 20
#define SBS 44                 // sbuf row stride in floats (41 used, 16B-aligned)
#define NBK 512                // blocks for dots kernel (2 per CU, 80 KiB LDS)
#define TBK 512                // threads per block = 8 waves
#define NWK (NBK * (TBK / 64)) // 4096 waves, 8 rows each (4 pairs)
#define NWSUM 2048             // commitment-sum grouping (original kernel's order)

// ---- butterfly stages: 1,2 via DPP quad_perm (VALU); 4,8,16,32 via shfl ----
__device__ __forceinline__ float bfly_xor1(float x) {
    return __int_as_float(__builtin_amdgcn_update_dpp(
        __float_as_int(x), __float_as_int(x), 0xB1, 0xF, 0xF, false)); // [1,0,3,2]
}
__device__ __forceinline__ float bfly_xor2(float x) {
    return __int_as_float(__builtin_amdgcn_update_dpp(
        __float_as_int(x), __float_as_int(x), 0x4E, 0xF, 0xF, false)); // [2,3,0,1]
}
// full 6-stage butterfly, same pairing/order as for(m=1;m<64;m<<=1) x+=shfl_xor(x,m)
__device__ __forceinline__ float bfly(float x) {
    x += bfly_xor1(x);
    x += bfly_xor2(x);
    x += __shfl_xor(x, 4, 64);
    x += __shfl_xor(x, 8, 64);
    x += __shfl_xor(x, 16, 64);
    x += __shfl_xor(x, 32, 64);
    return x;
}

// ---------------- kernel 1: precompute norm_keys, VK, VV ----------------
__global__ __launch_bounds__(1024) void pp_pre(
    const float* __restrict__ keys,
    const float* __restrict__ vals,
    float* __restrict__ nk,     // ws: normalized keys f32 [PP*D]
    float* __restrict__ vkf,    // ws: VK = v_q . k_norm_p, f32 [PP*PP]
    float* __restrict__ vvf)    // ws: VV = v_q . v_p,      f32 [PP*PP]
{
    __shared__ float nk_s[PP * D];
    __shared__ float nrm_s[PP];
    const int tid = threadIdx.x;

    if (tid < PP) {
        const float* kp = keys + tid * D;
        double s0 = 0.0, s1 = 0.0;
        for (int d = 0; d < D; d += 2) {
            s0 += (double)kp[d]     * (double)kp[d];
            s1 += (double)kp[d + 1] * (double)kp[d + 1];
        }
        nrm_s[tid] = sqrtf((float)(s0 + s1));
    }
    __syncthreads();

    for (int i = tid; i < PP * D; i += blockDim.x) {
        float x = keys[i] / nrm_s[i >> 10];
        nk_s[i] = x;
        nk[i]   = x;
    }
    __syncthreads();

    if (tid < 2 * PP * PP) {
        const int which = tid & 1;              // 0 -> VK, 1 -> VV
        const int rem   = tid >> 1;             // q*PP + p
        const int q = rem / PP, p = rem % PP;
        const float* vq    = vals + q * D;
        const float* other = which ? (vals + p * D) : (nk_s + p * D);
        double s0 = 0.0, s1 = 0.0;
        for (int d = 0; d < D; d += 2) {
            s0 += (double)vq[d]     * (double)other[d];
            s1 += (double)vq[d + 1] * (double)other[d + 1];
        }
        float r = (float)(s0 + s1);
        if (which) vvf[rem] = r; else vkf[rem] = r;
    }
}

// ------- kernel 2: all 41 dots, PAIR of rows, shared key+val fragments ------
__global__ __launch_bounds__(TBK) void pp_dots(
    const float* __restrict__ input,
    const float* __restrict__ vals,
    const float* __restrict__ nk,
    float* __restrict__ sbuf,   // [B][SBS]: 0..19 -> s, 20..39 -> rvp, 40 -> ||x||^2
    int B)
{
    __shared__ float s_keys[PP * D];   // 80 KiB -> 2 blocks/CU
    const int tid = threadIdx.x;
    {
        const float4* a = (const float4*)nk;
        float4* sa = (float4*)s_keys;
        for (int i = tid; i < PP * D / 4; i += TBK) sa[i] = a[i];
    }
    __syncthreads();

    const int lane = tid & 63;
    const int gw   = blockIdx.x * (TBK / 64) + (tid >> 6);

    for (int rowA = gw; rowA < B; rowA += 2 * NWK) {
        const int  rowB = rowA + NWK;
        const bool hasB = rowB < B;

        // load both rows (B falls back to A's data when absent; not written)
        const float4* ipA = (const float4*)(input + (size_t)rowA * D);
        float4 a0 = ipA[lane], a1 = ipA[lane + 64], a2 = ipA[lane + 128], a3 = ipA[lane + 192];
        const float4* ipB = (const float4*)(input + (size_t)(hasB ? rowB : rowA) * D);
        float4 b0 = ipB[lane], b1 = ipB[lane + 64], b2 = ipB[lane + 128], b3 = ipB[lane + 192];

        float rvA[16] = { a0.x,a0.y,a0.z,a0.w, a1.x,a1.y,a1.z,a1.w,
                          a2.x,a2.y,a2.z,a2.w, a3.x,a3.y,a3.z,a3.w };
        float rvB[16] = { b0.x,b0.y,b0.z,b0.w, b1.x,b1.y,b1.z,b1.w,
                          b2.x,b2.y,b2.z,b2.w, b3.x,b3.y,b3.z,b3.w };

        // self dots (f32 chains as original, reduce immediately)
        float sqA = 0.f;
#pragma unroll
        for (int i = 0; i < 16; i++) sqA = fmaf(rvA[i], rvA[i], sqA);
        sqA = bfly(sqA);
        float sqB = 0.f;
#pragma unroll
        for (int i = 0; i < 16; i++) sqB = fmaf(rvB[i], rvB[i], sqB);
        sqB = bfly(sqB);

        float oA = sqA, oB = sqB;   // lane 40 keeps these

        // ---- val dots: ONE fragment load feeds BOTH rows' f32 chains ----
#pragma unroll 1
        for (int p = 0; p < PP; p++) {
            const float4* vp = (const float4*)(vals + (size_t)p * D);
            float4 v0 = vp[lane], v1 = vp[lane + 64], v2 = vp[lane + 128], v3 = vp[lane + 192];
            float vl[16] = { v0.x,v0.y,v0.z,v0.w, v1.x,v1.y,v1.z,v1.w,
                             v2.x,v2.y,v2.z,v2.w, v3.x,v3.y,v3.z,v3.w };
            float abA = 0.f, abB = 0.f;
#pragma unroll
            for (int i = 0; i < 16; i++) abA = fmaf(rvA[i], vl[i], abA);
#pragma unroll
            for (int i = 0; i < 16; i++) abB = fmaf(rvB[i], vl[i], abB);
            // interleaved butterflies, each chain's order = original 6-stage
            abA += bfly_xor1(abA);        abB += bfly_xor1(abB);
            abA += bfly_xor2(abA);        abB += bfly_xor2(abB);
            abA += __shfl_xor(abA, 4, 64);  abB += __shfl_xor(abB, 4, 64);
            abA += __shfl_xor(abA, 8, 64);  abB += __shfl_xor(abB, 8, 64);
            abA += __shfl_xor(abA, 16, 64); abB += __shfl_xor(abB, 16, 64);
            abA += __shfl_xor(abA, 32, 64); abB += __shfl_xor(abB, 32, 64);
            oA = (lane == PP + p) ? abA : oA;
            oB = (lane == PP + p) ? abB : oB;
        }

        // ---- cvt once per row (exact); rvA/rvB die here ----
        double rdA[16], rdB[16];
#pragma unroll
        for (int i = 0; i < 16; i++) rdA[i] = (double)rvA[i];
#pragma unroll
        for (int i = 0; i < 16; i++) rdB[i] = (double)rvB[i];

        // ---- key dots: ONE ds_read fragment feeds BOTH rows' f64 chains ----
#pragma unroll 1
        for (int p = 0; p < PP; p++) {
            const float4* kp = (const float4*)(s_keys + p * D);
            float4 k0 = kp[lane], k1 = kp[lane + 64], k2 = kp[lane + 128], k3 = kp[lane + 192];
            float kk[16] = { k0.x,k0.y,k0.z,k0.w, k1.x,k1.y,k1.z,k1.w,
                             k2.x,k2.y,k2.z,k2.w, k3.x,k3.y,k3.z,k3.w };
            double accA = 0.0, accB = 0.0;
#pragma unroll
            for (int i = 0; i < 16; i++) accA = fma(rdA[i], (double)kk[i], accA);
#pragma unroll
            for (int i = 0; i < 16; i++) accB = fma(rdB[i], (double)kk[i], accB);
            float spA = (float)accA, spB = (float)accB;
            spA += bfly_xor1(spA);        spB += bfly_xor1(spB);
            spA += bfly_xor2(spA);        spB += bfly_xor2(spB);
            spA += __shfl_xor(spA, 4, 64);  spB += __shfl_xor(spB, 4, 64);
            spA += __shfl_xor(spA, 8, 64);  spB += __shfl_xor(spB, 8, 64);
            spA += __shfl_xor(spA, 16, 64); spB += __shfl_xor(spB, 16, 64);
            spA += __shfl_xor(spA, 32, 64); spB += __shfl_xor(spB, 32, 64);
            oA = (lane == p) ? spA : oA;
            oB = (lane == p) ? spB : oB;
        }

        if (lane < 2 * PP + 1) {
            sbuf[(size_t)rowA * SBS + lane] = oA;
            if (hasB) sbuf[(size_t)rowB * SBS + lane] = oB;
        }
    }
}

// ---------------- kernel 3: decide (1 LANE per row) ----------------
__global__ __launch_bounds__(256) void pp_decide(
    const float* __restrict__ sbuf,   // [B][SBS]
    const float* __restrict__ vkf,
    const float* __restrict__ vvf,
    float* __restrict__ out_idx,      // [B*K] as float
    float* __restrict__ cmrow,        // [B] per-row commitment (f32, exact values)
    int B, int K)
{
    __shared__ float vk_s[PP * PP];
    __shared__ float vv_s[PP * PP];
    for (int i = threadIdx.x; i < PP * PP; i += 256) { vk_s[i] = vkf[i]; vv_s[i] = vvf[i]; }
    __syncthreads();
    const int row = blockIdx.x * 256 + threadIdx.x;
    if (row >= B) return;

    const float4* rp = (const float4*)(sbuf + (size_t)row * SBS);
    float s[PP], rvp[PP];
    {
        float4 a0 = rp[0], a1 = rp[1], a2 = rp[2], a3 = rp[3], a4 = rp[4];
        float4 b0 = rp[5], b1 = rp[6], b2 = rp[7], b3 = rp[8], b4 = rp[9];
        s[0]=a0.x;  s[1]=a0.y;  s[2]=a0.z;  s[3]=a0.w;
        s[4]=a1.x;  s[5]=a1.y;  s[6]=a1.z;  s[7]=a1.w;
        s[8]=a2.x;  s[9]=a2.y;  s[10]=a2.z; s[11]=a2.w;
        s[12]=a3.x; s[13]=a3.y; s[14]=a3.z; s[15]=a3.w;
        s[16]=a4.x; s[17]=a4.y; s[18]=a4.z; s[19]=a4.w;
        rvp[0]=b0.x;  rvp[1]=b0.y;  rvp[2]=b0.z;  rvp[3]=b0.w;
        rvp[4]=b1.x;  rvp[5]=b1.y;  rvp[6]=b1.z;  rvp[7]=b1.w;
        rvp[8]=b2.x;  rvp[9]=b2.y;  rvp[10]=b2.z; rvp[11]=b2.w;
        rvp[12]=b3.x; rvp[13]=b3.y; rvp[14]=b3.z; rvp[15]=b3.w;
        rvp[16]=b4.x; rvp[17]=b4.y; rvp[18]=b4.z; rvp[19]=b4.w;
    }
    float rn2 = ((const float*)rp)[2 * PP];

    float cm = 0.f;
    for (int t = 0; t < K; t++) {
        float nrm = sqrtf(rn2);
        float sims[PP];
#pragma unroll
        for (int p = 0; p < PP; p++) sims[p] = s[p] / nrm;
        float mx = sims[0];
#pragma unroll
        for (int p = 1; p < PP; p++) mx = fmaxf(mx, sims[p]);
        float e[PP];
        float denom = 0.f;
#pragma unroll
        for (int p = 0; p < PP; p++) { e[p] = expf(sims[p] - mx); denom += e[p]; }
        float best = -1.f; int bi = 0;
#pragma unroll
        for (int p = 0; p < PP; p++) {
            float pr = e[p] / denom;
            if (pr > best) { best = pr; bi = p; }
        }
        cm += best;
        out_idx[(size_t)row * K + t] = (float)bi;

        if (t + 1 < K) {
            float rvbi = rvp[0];
#pragma unroll
            for (int p = 1; p < PP; p++) rvbi = (p == bi) ? rvp[p] : rvbi;
            rn2 = rn2 - 2.f * rvbi + vv_s[bi * PP + bi];
#pragma unroll
            for (int p = 0; p < PP; p++) { s[p] -= vk_s[bi * PP + p]; rvp[p] -= vv_s[bi * PP + p]; }
        }
    }
    cmrow[row] = cm;
}

// ---------------- kernel 4: wsum (original per-wave f64 sum order) ----------
__global__ __launch_bounds__(256) void pp_wsum(
    const float* __restrict__ cmrow, double* __restrict__ wsum, int B)
{
    const int g = blockIdx.x * 256 + threadIdx.x;   // 0..NWSUM-1
    if (g >= NWSUM) return;
    double s = 0.0;
    for (int r = g; r < B; r += NWSUM) s += (double)cmrow[r];  // same order as old csum
    wsum[g] = s;
}

// ---------------- kernel 5: broadcast writer (wave per (row,t) task) ---------
__global__ __launch_bounds__(256) void pp_bcast(
    const float* __restrict__ vals,
    const float* __restrict__ out_idx,
    float* __restrict__ out_sel,
    int nTask)
{
    const int lane = threadIdx.x & 63;
    const int wid  = blockIdx.x * 4 + (threadIdx.x >> 6);
    const int nw   = gridDim.x * 4;

    int task = wid;
    int bi = (task < nTask) ? (int)out_idx[task] : 0;
    while (task < nTask) {
        const int ntask = task + nw;
        const int nbi = (ntask < nTask) ? (int)out_idx[ntask] : 0;  // prefetch idx

        const float4* pv = (const float4*)(vals + (size_t)bi * D);
        float4* ob = (float4*)(out_sel + (size_t)task * D);
        float4 a = pv[lane], b = pv[lane + 64], c = pv[lane + 128], d = pv[lane + 192];
        ob[lane]       = a;
        ob[lane + 64]  = b;
        ob[lane + 128] = c;
        ob[lane + 192] = d;

        task = ntask; bi = nbi;
    }
}

// ---------------- kernel 6: loss reduce ----------------
__global__ __launch_bounds__(256) void pp_loss(
    const double* __restrict__ wsum, float* __restrict__ out_loss, int B)
{
    __shared__ double sh[4];
    const int tid = threadIdx.x;
    double s = 0.0;
    for (int i = tid; i < NWSUM; i += 256) s += wsum[i];
#pragma unroll
    for (int m = 1; m < 64; m <<= 1) s += __shfl_xor(s, m, 64);
    if ((tid & 63) == 0) sh[tid >> 6] = s;
    __syncthreads();
    if (tid == 0) {
        double tot = sh[0] + sh[1] + sh[2] + sh[3];
        out_loss[0] = (float)(-(tot / (double)B));
    }
}

extern "C" void kernel_launch(void* const* d_in, const int* in_sizes, int n_in,
                              void* d_out, int out_size, void* d_ws, size_t ws_size,
                              hipStream_t stream) {
    const float* input = (const float*)d_in[0];
    const float* keys  = (const float*)d_in[1];
    const float* vals  = (const float*)d_in[2];

    const int B = in_sizes[0] / D;                       // 32768
    const int K = (out_size - 1) / (B * (D + 1));        // 5

    float* out_sel  = (float*)d_out;
    const size_t selN = (size_t)B * K * D;
    float* out_loss = out_sel + selN;
    float* out_idx  = out_sel + selN + 1;

    char*  ws    = (char*)d_ws;
    float* nk    = (float*)ws;                           // PP*D f32 = 81920 B
    float* vkf   = nk + PP * D;                          // 400 f32
    float* vvf   = vkf + PP * PP;                        // 400 f32
    double* wsum = (double*)(ws + ((PP * D + 2 * PP * PP) * 4)); // 8-aligned

    // Large scratch lives INSIDE out_sel (regenerated in full by pp_bcast later):
    //   sbuf = [B][SBS] f32 (5.8 MB), cmrow = [B] f32 (128 KB) — far below selN.
    float* sbuf  = out_sel;
    float* cmrow = out_sel + (size_t)B * SBS;

    const int nTask = B * K;

    pp_pre   <<<1, 1024, 0, stream>>>(keys, vals, nk, vkf, vvf);
    pp_dots  <<<NBK, TBK, 0, stream>>>(input, vals, nk, sbuf, B);
    pp_decide<<<(B + 255) / 256, 256, 0, stream>>>(sbuf, vkf, vvf, out_idx, cmrow, B, K);
    pp_wsum  <<<(NWSUM + 255) / 256, 256, 0, stream>>>(cmrow, wsum, B);
    pp_bcast <<<2048, 256, 0, stream>>>(vals, out_idx, out_sel, nTask);
    pp_loss  <<<1, 256, 0, stream>>>(wsum, out_loss, B);
}

// Round 11
// 303.818 us; speedup vs baseline: 1.5206x; 1.1367x over previous
//
#include <hip/hip_runtime.h>

// PromptPool: B=32768 rows, D=1024, P=20 prompts, K=5 rounds.
// Phase split:
//   pp_pre1   - key norms + normalized keys nk (1 block; only serial part)
//   pp_pre2   - VK/VV cross-dot tables: 800 independent serial f64 dots spread
//               across 13 blocks (was 1 block = 1 CU; now ~2 us)
//   pp_dots   - PAIR of rows per iteration (R10 structure): self dots -> val
//               dots (shared fragment) -> cvt -> key dots (shared ds_read
//               fragment, f64). p-loops `unroll 1` (R6). Butterfly stages
//               1,2,8 on VALU via DPP (quad_perm xor1/xor2 + row_ror:8 == xor8),
//               stages 4,16,32 via shfl. Same adds, same order -> bit-identical.
//   pp_decide - one LANE per row; block's 45 KB sbuf slab staged coalesced
//               into LDS first (kills strided-global latency at 0.5 blk/CU)
//   pp_wsum   - original per-wave f64 commitment grouping (stride 2048)
//   pp_bcast  - pure broadcast: out_sel[row,t] = vals[idx[row,t]]
//   pp_loss   - final reduction

#define D  1024
#define PP 20
#define SBS 44                 // sbuf row stride in floats (41 used, 16B-aligned)
#define NBK 512                // blocks for dots kernel (2 per CU, 80 KiB LDS)
#define TBK 512                // threads per block = 8 waves
#define NWK (NBK * (TBK / 64)) // 4096 waves, 8 rows each (4 pairs)
#define NWSUM 2048             // commitment-sum grouping (original kernel's order)

// ---- butterfly stages: 1,2 quad_perm; 8 row_ror:8 (==xor8); 4,16,32 shfl ----
__device__ __forceinline__ float bfly_xor1(float x) {
    return __int_as_float(__builtin_amdgcn_update_dpp(
        __float_as_int(x), __float_as_int(x), 0xB1, 0xF, 0xF, false)); // quad [1,0,3,2]
}
__device__ __forceinline__ float bfly_xor2(float x) {
    return __int_as_float(__builtin_amdgcn_update_dpp(
        __float_as_int(x), __float_as_int(x), 0x4E, 0xF, 0xF, false)); // quad [2,3,0,1]
}
__device__ __forceinline__ float bfly_xor8(float x) {
    // row_ror:8 within 16-lane row: (i+8)&15 == i^8 exactly
    return __int_as_float(__builtin_amdgcn_update_dpp(
        __float_as_int(x), __float_as_int(x), 0x128, 0xF, 0xF, false));
}
// full 6-stage butterfly, same pairing/order as for(m=1;m<64;m<<=1) x+=shfl_xor(x,m)
__device__ __forceinline__ float bfly(float x) {
    x += bfly_xor1(x);
    x += bfly_xor2(x);
    x += __shfl_xor(x, 4, 64);
    x += bfly_xor8(x);
    x += __shfl_xor(x, 16, 64);
    x += __shfl_xor(x, 32, 64);
    return x;
}

// ---------------- kernel 1a: key norms + normalized keys ----------------
__global__ __launch_bounds__(1024) void pp_pre1(
    const float* __restrict__ keys,
    float* __restrict__ nk)     // ws: normalized keys f32 [PP*D]
{
    __shared__ float nrm_s[PP];
    const int tid = threadIdx.x;

    if (tid < PP) {
        const float* kp = keys + tid * D;
        double s0 = 0.0, s1 = 0.0;
        for (int d = 0; d < D; d += 2) {
            s0 += (double)kp[d]     * (double)kp[d];
            s1 += (double)kp[d + 1] * (double)kp[d + 1];
        }
        nrm_s[tid] = sqrtf((float)(s0 + s1));
    }
    __syncthreads();

    for (int i = tid; i < PP * D; i += blockDim.x)
        nk[i] = keys[i] / nrm_s[i >> 10];     // IEEE f32 divide, as reference
}

// ---------------- kernel 1b: VK/VV tables, parallel over 13 blocks -----------
__global__ __launch_bounds__(64) void pp_pre2(
    const float* __restrict__ nk,
    const float* __restrict__ vals,
    float* __restrict__ vkf,    // VK = v_q . k_norm_p
    float* __restrict__ vvf)    // VV = v_q . v_p
{
    const int tid = blockIdx.x * 64 + threadIdx.x;
    if (tid >= 2 * PP * PP) return;
    const int which = tid & 1;              // 0 -> VK, 1 -> VV
    const int rem   = tid >> 1;             // q*PP + p
    const int q = rem / PP, p = rem % PP;
    const float* vq    = vals + q * D;
    const float* other = which ? (vals + p * D) : (nk + p * D);
    double s0 = 0.0, s1 = 0.0;
    for (int d = 0; d < D; d += 2) {        // identical loop -> identical bits
        s0 += (double)vq[d]     * (double)other[d];
        s1 += (double)vq[d + 1] * (double)other[d + 1];
    }
    float r = (float)(s0 + s1);
    if (which) vvf[rem] = r; else vkf[rem] = r;
}

// ------- kernel 2: all 41 dots, PAIR of rows, shared key+val fragments ------
__global__ __launch_bounds__(TBK) void pp_dots(
    const float* __restrict__ input,
    const float* __restrict__ vals,
    const float* __restrict__ nk,
    float* __restrict__ sbuf,   // [B][SBS]: 0..19 -> s, 20..39 -> rvp, 40 -> ||x||^2
    int B)
{
    __shared__ float s_keys[PP * D];   // 80 KiB -> 2 blocks/CU
    const int tid = threadIdx.x;
    {
        const float4* a = (const float4*)nk;
        float4* sa = (float4*)s_keys;
        for (int i = tid; i < PP * D / 4; i += TBK) sa[i] = a[i];
    }
    __syncthreads();

    const int lane = tid & 63;
    const int gw   = blockIdx.x * (TBK / 64) + (tid >> 6);

    for (int rowA = gw; rowA < B; rowA += 2 * NWK) {
        const int  rowB = rowA + NWK;
        const bool hasB = rowB < B;

        const float4* ipA = (const float4*)(input + (size_t)rowA * D);
        float4 a0 = ipA[lane], a1 = ipA[lane + 64], a2 = ipA[lane + 128], a3 = ipA[lane + 192];
        const float4* ipB = (const float4*)(input + (size_t)(hasB ? rowB : rowA) * D);
        float4 b0 = ipB[lane], b1 = ipB[lane + 64], b2 = ipB[lane + 128], b3 = ipB[lane + 192];

        float rvA[16] = { a0.x,a0.y,a0.z,a0.w, a1.x,a1.y,a1.z,a1.w,
                          a2.x,a2.y,a2.z,a2.w, a3.x,a3.y,a3.z,a3.w };
        float rvB[16] = { b0.x,b0.y,b0.z,b0.w, b1.x,b1.y,b1.z,b1.w,
                          b2.x,b2.y,b2.z,b2.w, b3.x,b3.y,b3.z,b3.w };

        // self dots (f32 chains as original, reduce immediately)
        float sqA = 0.f;
#pragma unroll
        for (int i = 0; i < 16; i++) sqA = fmaf(rvA[i], rvA[i], sqA);
        sqA = bfly(sqA);
        float sqB = 0.f;
#pragma unroll
        for (int i = 0; i < 16; i++) sqB = fmaf(rvB[i], rvB[i], sqB);
        sqB = bfly(sqB);

        float oA = sqA, oB = sqB;   // lane 40 keeps these

        // ---- val dots: ONE fragment load feeds BOTH rows' f32 chains ----
#pragma unroll 1
        for (int p = 0; p < PP; p++) {
            const float4* vp = (const float4*)(vals + (size_t)p * D);
            float4 v0 = vp[lane], v1 = vp[lane + 64], v2 = vp[lane + 128], v3 = vp[lane + 192];
            float vl[16] = { v0.x,v0.y,v0.z,v0.w, v1.x,v1.y,v1.z,v1.w,
                             v2.x,v2.y,v2.z,v2.w, v3.x,v3.y,v3.z,v3.w };
            float abA = 0.f, abB = 0.f;
#pragma unroll
            for (int i = 0; i < 16; i++) abA = fmaf(rvA[i], vl[i], abA);
#pragma unroll
            for (int i = 0; i < 16; i++) abB = fmaf(rvB[i], vl[i], abB);
            abA += bfly_xor1(abA);          abB += bfly_xor1(abB);
            abA += bfly_xor2(abA);          abB += bfly_xor2(abB);
            abA += __shfl_xor(abA, 4, 64);  abB += __shfl_xor(abB, 4, 64);
            abA += bfly_xor8(abA);          abB += bfly_xor8(abB);
            abA += __shfl_xor(abA, 16, 64); abB += __shfl_xor(abB, 16, 64);
            abA += __shfl_xor(abA, 32, 64); abB += __shfl_xor(abB, 32, 64);
            oA = (lane == PP + p) ? abA : oA;
            oB = (lane == PP + p) ? abB : oB;
        }

        // ---- cvt once per row (exact); rvA/rvB die here ----
        double rdA[16], rdB[16];
#pragma unroll
        for (int i = 0; i < 16; i++) rdA[i] = (double)rvA[i];
#pragma unroll
        for (int i = 0; i < 16; i++) rdB[i] = (double)rvB[i];

        // ---- key dots: ONE ds_read fragment feeds BOTH rows' f64 chains ----
#pragma unroll 1
        for (int p = 0; p < PP; p++) {
            const float4* kp = (const float4*)(s_keys + p * D);
            float4 k0 = kp[lane], k1 = kp[lane + 64], k2 = kp[lane + 128], k3 = kp[lane + 192];
            float kk[16] = { k0.x,k0.y,k0.z,k0.w, k1.x,k1.y,k1.z,k1.w,
                             k2.x,k2.y,k2.z,k2.w, k3.x,k3.y,k3.z,k3.w };
            double accA = 0.0, accB = 0.0;
#pragma unroll
            for (int i = 0; i < 16; i++) accA = fma(rdA[i], (double)kk[i], accA);
#pragma unroll
            for (int i = 0; i < 16; i++) accB = fma(rdB[i], (double)kk[i], accB);
            float spA = (float)accA, spB = (float)accB;
            spA += bfly_xor1(spA);          spB += bfly_xor1(spB);
            spA += bfly_xor2(spA);          spB += bfly_xor2(spB);
            spA += __shfl_xor(spA, 4, 64);  spB += __shfl_xor(spB, 4, 64);
            spA += bfly_xor8(spA);          spB += bfly_xor8(spB);
            spA += __shfl_xor(spA, 16, 64); spB += __shfl_xor(spB, 16, 64);
            spA += __shfl_xor(spA, 32, 64); spB += __shfl_xor(spB, 32, 64);
            oA = (lane == p) ? spA : oA;
            oB = (lane == p) ? spB : oB;
        }

        if (lane < 2 * PP + 1) {
            sbuf[(size_t)rowA * SBS + lane] = oA;
            if (hasB) sbuf[(size_t)rowB * SBS + lane] = oB;
        }
    }
}

// ------- kernel 3: decide (1 LANE per row; block slab staged via LDS) -------
__global__ __launch_bounds__(256) void pp_decide(
    const float* __restrict__ sbuf,   // [B][SBS]
    const float* __restrict__ vkf,
    const float* __restrict__ vvf,
    float* __restrict__ out_idx,      // [B*K] as float
    float* __restrict__ cmrow,        // [B] per-row commitment (f32, exact values)
    int B, int K)
{
    __shared__ float vk_s[PP * PP];
    __shared__ float vv_s[PP * PP];
    __shared__ float sb_s[256 * SBS];          // 45056 B, coalesced-staged slab
    for (int i = threadIdx.x; i < PP * PP; i += 256) { vk_s[i] = vkf[i]; vv_s[i] = vvf[i]; }

    const int base  = blockIdx.x * 256;
    const int nrows = (B - base < 256) ? (B - base) : 256;
    {
        const float4* g4 = (const float4*)(sbuf + (size_t)base * SBS);
        float4* s4 = (float4*)sb_s;
        const int nf4 = nrows * (SBS / 4);     // SBS=44 -> 11 float4/row
        for (int i = threadIdx.x; i < nf4; i += 256) s4[i] = g4[i];
    }
    __syncthreads();
    const int row = base + threadIdx.x;
    if (row >= B) return;

    const float4* rp = (const float4*)(sb_s + threadIdx.x * SBS);
    float s[PP], rvp[PP];
    {
        float4 a0 = rp[0], a1 = rp[1], a2 = rp[2], a3 = rp[3], a4 = rp[4];
        float4 b0 = rp[5], b1 = rp[6], b2 = rp[7], b3 = rp[8], b4 = rp[9];
        s[0]=a0.x;  s[1]=a0.y;  s[2]=a0.z;  s[3]=a0.w;
        s[4]=a1.x;  s[5]=a1.y;  s[6]=a1.z;  s[7]=a1.w;
        s[8]=a2.x;  s[9]=a2.y;  s[10]=a2.z; s[11]=a2.w;
        s[12]=a3.x; s[13]=a3.y; s[14]=a3.z; s[15]=a3.w;
        s[16]=a4.x; s[17]=a4.y; s[18]=a4.z; s[19]=a4.w;
        rvp[0]=b0.x;  rvp[1]=b0.y;  rvp[2]=b0.z;  rvp[3]=b0.w;
        rvp[4]=b1.x;  rvp[5]=b1.y;  rvp[6]=b1.z;  rvp[7]=b1.w;
        rvp[8]=b2.x;  rvp[9]=b2.y;  rvp[10]=b2.z; rvp[11]=b2.w;
        rvp[12]=b3.x; rvp[13]=b3.y; rvp[14]=b3.z; rvp[15]=b3.w;
        rvp[16]=b4.x; rvp[17]=b4.y; rvp[18]=b4.z; rvp[19]=b4.w;
    }
    float rn2 = ((const float*)rp)[2 * PP];

    float cm = 0.f;
    for (int t = 0; t < K; t++) {
        float nrm = sqrtf(rn2);
        float sims[PP];
#pragma unroll
        for (int p = 0; p < PP; p++) sims[p] = s[p] / nrm;
        float mx = sims[0];
#pragma unroll
        for (int p = 1; p < PP; p++) mx = fmaxf(mx, sims[p]);
        float e[PP];
        float denom = 0.f;
#pragma unroll
        for (int p = 0; p < PP; p++) { e[p] = expf(sims[p] - mx); denom += e[p]; }
        float best = -1.f; int bi = 0;
#pragma unroll
        for (int p = 0; p < PP; p++) {
            float pr = e[p] / denom;
            if (pr > best) { best = pr; bi = p; }
        }
        cm += best;
        out_idx[(size_t)row * K + t] = (float)bi;

        if (t + 1 < K) {
            float rvbi = rvp[0];
#pragma unroll
            for (int p = 1; p < PP; p++) rvbi = (p == bi) ? rvp[p] : rvbi;
            rn2 = rn2 - 2.f * rvbi + vv_s[bi * PP + bi];
#pragma unroll
            for (int p = 0; p < PP; p++) { s[p] -= vk_s[bi * PP + p]; rvp[p] -= vv_s[bi * PP + p]; }
        }
    }
    cmrow[row] = cm;
}

// ---------------- kernel 4: wsum (original per-wave f64 sum order) ----------
__global__ __launch_bounds__(256) void pp_wsum(
    const float* __restrict__ cmrow, double* __restrict__ wsum, int B)
{
    const int g = blockIdx.x * 256 + threadIdx.x;   // 0..NWSUM-1
    if (g >= NWSUM) return;
    double s = 0.0;
    for (int r = g; r < B; r += NWSUM) s += (double)cmrow[r];  // same order as old csum
    wsum[g] = s;
}

// ---------------- kernel 5: broadcast writer (wave per (row,t) task) ---------
__global__ __launch_bounds__(256) void pp_bcast(
    const float* __restrict__ vals,
    const float* __restrict__ out_idx,
    float* __restrict__ out_sel,
    int nTask)
{
    const int lane = threadIdx.x & 63;
    const int wid  = blockIdx.x * 4 + (threadIdx.x >> 6);
    const int nw   = gridDim.x * 4;

    int task = wid;
    int bi = (task < nTask) ? (int)out_idx[task] : 0;
    while (task < nTask) {
        const int ntask = task + nw;
        const int nbi = (ntask < nTask) ? (int)out_idx[ntask] : 0;  // prefetch idx

        const float4* pv = (const float4*)(vals + (size_t)bi * D);
        float4* ob = (float4*)(out_sel + (size_t)task * D);
        float4 a = pv[lane], b = pv[lane + 64], c = pv[lane + 128], d = pv[lane + 192];
        ob[lane]       = a;
        ob[lane + 64]  = b;
        ob[lane + 128] = c;
        ob[lane + 192] = d;

        task = ntask; bi = nbi;
    }
}

// ---------------- kernel 6: loss reduce ----------------
__global__ __launch_bounds__(256) void pp_loss(
    const double* __restrict__ wsum, float* __restrict__ out_loss, int B)
{
    __shared__ double sh[4];
    const int tid = threadIdx.x;
    double s = 0.0;
    for (int i = tid; i < NWSUM; i += 256) s += wsum[i];
#pragma unroll
    for (int m = 1; m < 64; m <<= 1) s += __shfl_xor(s, m, 64);
    if ((tid & 63) == 0) sh[tid >> 6] = s;
    __syncthreads();
    if (tid == 0) {
        double tot = sh[0] + sh[1] + sh[2] + sh[3];
        out_loss[0] = (float)(-(tot / (double)B));
    }
}

extern "C" void kernel_launch(void* const* d_in, const int* in_sizes, int n_in,
                              void* d_out, int out_size, void* d_ws, size_t ws_size,
                              hipStream_t stream) {
    const float* input = (const float*)d_in[0];
    const float* keys  = (const float*)d_in[1];
    const float* vals  = (const float*)d_in[2];

    const int B = in_sizes[0] / D;                       // 32768
    const int K = (out_size - 1) / (B * (D + 1));        // 5

    float* out_sel  = (float*)d_out;
    const size_t selN = (size_t)B * K * D;
    float* out_loss = out_sel + selN;
    float* out_idx  = out_sel + selN + 1;

    char*  ws    = (char*)d_ws;
    float* nk    = (float*)ws;                           // PP*D f32 = 81920 B
    float* vkf   = nk + PP * D;                          // 400 f32
    float* vvf   = vkf + PP * PP;                        // 400 f32
    double* wsum = (double*)(ws + ((PP * D + 2 * PP * PP) * 4)); // 8-aligned

    // Large scratch lives INSIDE out_sel (regenerated in full by pp_bcast later):
    //   sbuf = [B][SBS] f32 (5.8 MB), cmrow = [B] f32 (128 KB) — far below selN.
    float* sbuf  = out_sel;
    float* cmrow = out_sel + (size_t)B * SBS;

    const int nTask = B * K;

    pp_pre1  <<<1, 1024, 0, stream>>>(keys, nk);
    pp_pre2  <<<(2 * PP * PP + 63) / 64, 64, 0, stream>>>(nk, vals, vkf, vvf);
    pp_dots  <<<NBK, TBK, 0, stream>>>(input, vals, nk, sbuf, B);
    pp_decide<<<(B + 255) / 256, 256, 0, stream>>>(sbuf, vkf, vvf, out_idx, cmrow, B, K);
    pp_wsum  <<<(NWSUM + 255) / 256, 256, 0, stream>>>(cmrow, wsum, B);
    pp_bcast <<<2048, 256, 0, stream>>>(vals, out_idx, out_sel, nTask);
    pp_loss  <<<1, 256, 0, stream>>>(wsum, out_loss, B);
}

// Round 12
// 299.735 us; speedup vs baseline: 1.5413x; 1.0136x over previous
//
#include <hip/hip_runtime.h>

// PromptPool: B=32768 rows, D=1024, P=20 prompts, K=5 rounds.
// Phase split:
//   pp_pre1   - key norms + normalized keys nk (1 block; only serial part)
//   pp_pre2   - VK/VV cross-dot tables across 13 blocks
//   pp_dots   - PAIR of rows per iteration: val dots (shared fragment,
//               unroll 2 -> 4 interleaved butterfly chains + batched L2 loads)
//               -> self dots (overlap with cvt) -> cvt -> key dots (shared
//               ds_read fragment, f64, unroll 1: rd[64] live). Butterfly
//               stages 1,2,8 on VALU via DPP; 4,16,32 via shfl (LDS).
//   pp_decide - one LANE per row; 256 blocks x 128 thr (all CUs), slab in LDS
//   pp_wsum   - original per-wave f64 commitment grouping (stride 2048)
//   pp_bcast  - pure broadcast: out_sel[row,t] = vals[idx[row,t]]
//   pp_loss   - final reduction
//
// R12: val loop unroll 2 (halves per-iter L2 stall + butterfly latency
// exposure; live ~80 regs, safe), sq moved after val loop (its DS chain
// overlaps the cvts), decide grid fills all 256 CUs.

#define D  1024
#define PP 20
#define SBS 44                 // sbuf row stride in floats (41 used, 16B-aligned)
#define NBK 512                // blocks for dots kernel (2 per CU, 80 KiB LDS)
#define TBK 512                // threads per block = 8 waves
#define NWK (NBK * (TBK / 64)) // 4096 waves, 8 rows each (4 pairs)
#define NWSUM 2048             // commitment-sum grouping (original kernel's order)
#define TDEC 128               // decide threads per block (256 blocks -> all CUs)

// ---- butterfly stages: 1,2 quad_perm; 8 row_ror:8 (==xor8); 4,16,32 shfl ----
__device__ __forceinline__ float bfly_xor1(float x) {
    return __int_as_float(__builtin_amdgcn_update_dpp(
        __float_as_int(x), __float_as_int(x), 0xB1, 0xF, 0xF, false)); // quad [1,0,3,2]
}
__device__ __forceinline__ float bfly_xor2(float x) {
    return __int_as_float(__builtin_amdgcn_update_dpp(
        __float_as_int(x), __float_as_int(x), 0x4E, 0xF, 0xF, false)); // quad [2,3,0,1]
}
__device__ __forceinline__ float bfly_xor8(float x) {
    // row_ror:8 within 16-lane row: (i+8)&15 == i^8 exactly
    return __int_as_float(__builtin_amdgcn_update_dpp(
        __float_as_int(x), __float_as_int(x), 0x128, 0xF, 0xF, false));
}
// full 6-stage butterfly, same pairing/order as for(m=1;m<64;m<<=1) x+=shfl_xor(x,m)
__device__ __forceinline__ float bfly(float x) {
    x += bfly_xor1(x);
    x += bfly_xor2(x);
    x += __shfl_xor(x, 4, 64);
    x += bfly_xor8(x);
    x += __shfl_xor(x, 16, 64);
    x += __shfl_xor(x, 32, 64);
    return x;
}

// ---------------- kernel 1a: key norms + normalized keys ----------------
__global__ __launch_bounds__(1024) void pp_pre1(
    const float* __restrict__ keys,
    float* __restrict__ nk)     // ws: normalized keys f32 [PP*D]
{
    __shared__ float nrm_s[PP];
    const int tid = threadIdx.x;

    if (tid < PP) {
        const float* kp = keys + tid * D;
        double s0 = 0.0, s1 = 0.0;
        for (int d = 0; d < D; d += 2) {
            s0 += (double)kp[d]     * (double)kp[d];
            s1 += (double)kp[d + 1] * (double)kp[d + 1];
        }
        nrm_s[tid] = sqrtf((float)(s0 + s1));
    }
    __syncthreads();

    for (int i = tid; i < PP * D; i += blockDim.x)
        nk[i] = keys[i] / nrm_s[i >> 10];     // IEEE f32 divide, as reference
}

// ---------------- kernel 1b: VK/VV tables, parallel over 13 blocks -----------
__global__ __launch_bounds__(64) void pp_pre2(
    const float* __restrict__ nk,
    const float* __restrict__ vals,
    float* __restrict__ vkf,    // VK = v_q . k_norm_p
    float* __restrict__ vvf)    // VV = v_q . v_p
{
    const int tid = blockIdx.x * 64 + threadIdx.x;
    if (tid >= 2 * PP * PP) return;
    const int which = tid & 1;              // 0 -> VK, 1 -> VV
    const int rem   = tid >> 1;             // q*PP + p
    const int q = rem / PP, p = rem % PP;
    const float* vq    = vals + q * D;
    const float* other = which ? (vals + p * D) : (nk + p * D);
    double s0 = 0.0, s1 = 0.0;
    for (int d = 0; d < D; d += 2) {        // identical loop -> identical bits
        s0 += (double)vq[d]     * (double)other[d];
        s1 += (double)vq[d + 1] * (double)other[d + 1];
    }
    float r = (float)(s0 + s1);
    if (which) vvf[rem] = r; else vkf[rem] = r;
}

// ------- kernel 2: all 41 dots, PAIR of rows, shared key+val fragments ------
__global__ __launch_bounds__(TBK) void pp_dots(
    const float* __restrict__ input,
    const float* __restrict__ vals,
    const float* __restrict__ nk,
    float* __restrict__ sbuf,   // [B][SBS]: 0..19 -> s, 20..39 -> rvp, 40 -> ||x||^2
    int B)
{
    __shared__ float s_keys[PP * D];   // 80 KiB -> 2 blocks/CU
    const int tid = threadIdx.x;
    {
        const float4* a = (const float4*)nk;
        float4* sa = (float4*)s_keys;
        for (int i = tid; i < PP * D / 4; i += TBK) sa[i] = a[i];
    }
    __syncthreads();

    const int lane = tid & 63;
    const int gw   = blockIdx.x * (TBK / 64) + (tid >> 6);

    for (int rowA = gw; rowA < B; rowA += 2 * NWK) {
        const int  rowB = rowA + NWK;
        const bool hasB = rowB < B;

        const float4* ipA = (const float4*)(input + (size_t)rowA * D);
        float4 a0 = ipA[lane], a1 = ipA[lane + 64], a2 = ipA[lane + 128], a3 = ipA[lane + 192];
        const float4* ipB = (const float4*)(input + (size_t)(hasB ? rowB : rowA) * D);
        float4 b0 = ipB[lane], b1 = ipB[lane + 64], b2 = ipB[lane + 128], b3 = ipB[lane + 192];

        float rvA[16] = { a0.x,a0.y,a0.z,a0.w, a1.x,a1.y,a1.z,a1.w,
                          a2.x,a2.y,a2.z,a2.w, a3.x,a3.y,a3.z,a3.w };
        float rvB[16] = { b0.x,b0.y,b0.z,b0.w, b1.x,b1.y,b1.z,b1.w,
                          b2.x,b2.y,b2.z,b2.w, b3.x,b3.y,b3.z,b3.w };

        float oA = 0.f, oB = 0.f;

        // ---- val dots: ONE fragment load feeds BOTH rows' f32 chains.
        //      unroll 2: two iterations' loads batch, 4 butterfly chains
        //      interleave (halves L2-stall + DS-latency exposure). ----
#pragma unroll 2
        for (int p = 0; p < PP; p++) {
            const float4* vp = (const float4*)(vals + (size_t)p * D);
            float4 v0 = vp[lane], v1 = vp[lane + 64], v2 = vp[lane + 128], v3 = vp[lane + 192];
            float vl[16] = { v0.x,v0.y,v0.z,v0.w, v1.x,v1.y,v1.z,v1.w,
                             v2.x,v2.y,v2.z,v2.w, v3.x,v3.y,v3.z,v3.w };
            float abA = 0.f, abB = 0.f;
#pragma unroll
            for (int i = 0; i < 16; i++) abA = fmaf(rvA[i], vl[i], abA);
#pragma unroll
            for (int i = 0; i < 16; i++) abB = fmaf(rvB[i], vl[i], abB);
            abA += bfly_xor1(abA);          abB += bfly_xor1(abB);
            abA += bfly_xor2(abA);          abB += bfly_xor2(abB);
            abA += __shfl_xor(abA, 4, 64);  abB += __shfl_xor(abB, 4, 64);
            abA += bfly_xor8(abA);          abB += bfly_xor8(abB);
            abA += __shfl_xor(abA, 16, 64); abB += __shfl_xor(abB, 16, 64);
            abA += __shfl_xor(abA, 32, 64); abB += __shfl_xor(abB, 32, 64);
            oA = (lane == PP + p) ? abA : oA;
            oB = (lane == PP + p) ? abB : oB;
        }

        // ---- self dots here: their DS butterfly chains overlap the cvts ----
        float sqA = 0.f;
#pragma unroll
        for (int i = 0; i < 16; i++) sqA = fmaf(rvA[i], rvA[i], sqA);
        sqA = bfly(sqA);
        float sqB = 0.f;
#pragma unroll
        for (int i = 0; i < 16; i++) sqB = fmaf(rvB[i], rvB[i], sqB);
        sqB = bfly(sqB);
        oA = (lane == 2 * PP) ? sqA : oA;
        oB = (lane == 2 * PP) ? sqB : oB;

        // ---- cvt once per row (exact); rvA/rvB die here ----
        double rdA[16], rdB[16];
#pragma unroll
        for (int i = 0; i < 16; i++) rdA[i] = (double)rvA[i];
#pragma unroll
        for (int i = 0; i < 16; i++) rdB[i] = (double)rvB[i];

        // ---- key dots: ONE ds_read fragment feeds BOTH rows' f64 chains ----
#pragma unroll 1
        for (int p = 0; p < PP; p++) {     // rd[64] live -> keep unroll 1 (R6)
            const float4* kp = (const float4*)(s_keys + p * D);
            float4 k0 = kp[lane], k1 = kp[lane + 64], k2 = kp[lane + 128], k3 = kp[lane + 192];
            float kk[16] = { k0.x,k0.y,k0.z,k0.w, k1.x,k1.y,k1.z,k1.w,
                             k2.x,k2.y,k2.z,k2.w, k3.x,k3.y,k3.z,k3.w };
            double accA = 0.0, accB = 0.0;
#pragma unroll
            for (int i = 0; i < 16; i++) accA = fma(rdA[i], (double)kk[i], accA);
#pragma unroll
            for (int i = 0; i < 16; i++) accB = fma(rdB[i], (double)kk[i], accB);
            float spA = (float)accA, spB = (float)accB;
            spA += bfly_xor1(spA);          spB += bfly_xor1(spB);
            spA += bfly_xor2(spA);          spB += bfly_xor2(spB);
            spA += __shfl_xor(spA, 4, 64);  spB += __shfl_xor(spB, 4, 64);
            spA += bfly_xor8(spA);          spB += bfly_xor8(spB);
            spA += __shfl_xor(spA, 16, 64); spB += __shfl_xor(spB, 16, 64);
            spA += __shfl_xor(spA, 32, 64); spB += __shfl_xor(spB, 32, 64);
            oA = (lane == p) ? spA : oA;
            oB = (lane == p) ? spB : oB;
        }

        if (lane < 2 * PP + 1) {
            sbuf[(size_t)rowA * SBS + lane] = oA;
            if (hasB) sbuf[(size_t)rowB * SBS + lane] = oB;
        }
    }
}

// ------- kernel 3: decide (1 LANE per row; 256 blocks x 128 thr) ------------
__global__ __launch_bounds__(TDEC) void pp_decide(
    const float* __restrict__ sbuf,   // [B][SBS]
    const float* __restrict__ vkf,
    const float* __restrict__ vvf,
    float* __restrict__ out_idx,      // [B*K] as float
    float* __restrict__ cmrow,        // [B] per-row commitment (f32, exact values)
    int B, int K)
{
    __shared__ float vk_s[PP * PP];
    __shared__ float vv_s[PP * PP];
    __shared__ float sb_s[TDEC * SBS];         // 22528 B coalesced-staged slab
    for (int i = threadIdx.x; i < PP * PP; i += TDEC) { vk_s[i] = vkf[i]; vv_s[i] = vvf[i]; }

    const int base  = blockIdx.x * TDEC;
    const int nrows = (B - base < TDEC) ? (B - base) : TDEC;
    {
        const float4* g4 = (const float4*)(sbuf + (size_t)base * SBS);
        float4* s4 = (float4*)sb_s;
        const int nf4 = nrows * (SBS / 4);     // 11 float4/row
        for (int i = threadIdx.x; i < nf4; i += TDEC) s4[i] = g4[i];
    }
    __syncthreads();
    const int row = base + threadIdx.x;
    if (row >= B) return;

    const float4* rp = (const float4*)(sb_s + threadIdx.x * SBS);
    float s[PP], rvp[PP];
    {
        float4 a0 = rp[0], a1 = rp[1], a2 = rp[2], a3 = rp[3], a4 = rp[4];
        float4 b0 = rp[5], b1 = rp[6], b2 = rp[7], b3 = rp[8], b4 = rp[9];
        s[0]=a0.x;  s[1]=a0.y;  s[2]=a0.z;  s[3]=a0.w;
        s[4]=a1.x;  s[5]=a1.y;  s[6]=a1.z;  s[7]=a1.w;
        s[8]=a2.x;  s[9]=a2.y;  s[10]=a2.z; s[11]=a2.w;
        s[12]=a3.x; s[13]=a3.y; s[14]=a3.z; s[15]=a3.w;
        s[16]=a4.x; s[17]=a4.y; s[18]=a4.z; s[19]=a4.w;
        rvp[0]=b0.x;  rvp[1]=b0.y;  rvp[2]=b0.z;  rvp[3]=b0.w;
        rvp[4]=b1.x;  rvp[5]=b1.y;  rvp[6]=b1.z;  rvp[7]=b1.w;
        rvp[8]=b2.x;  rvp[9]=b2.y;  rvp[10]=b2.z; rvp[11]=b2.w;
        rvp[12]=b3.x; rvp[13]=b3.y; rvp[14]=b3.z; rvp[15]=b3.w;
        rvp[16]=b4.x; rvp[17]=b4.y; rvp[18]=b4.z; rvp[19]=b4.w;
    }
    float rn2 = ((const float*)rp)[2 * PP];

    float cm = 0.f;
    for (int t = 0; t < K; t++) {
        float nrm = sqrtf(rn2);
        float sims[PP];
#pragma unroll
        for (int p = 0; p < PP; p++) sims[p] = s[p] / nrm;
        float mx = sims[0];
#pragma unroll
        for (int p = 1; p < PP; p++) mx = fmaxf(mx, sims[p]);
        float e[PP];
        float denom = 0.f;
#pragma unroll
        for (int p = 0; p < PP; p++) { e[p] = expf(sims[p] - mx); denom += e[p]; }
        float best = -1.f; int bi = 0;
#pragma unroll
        for (int p = 0; p < PP; p++) {
            float pr = e[p] / denom;
            if (pr > best) { best = pr; bi = p; }
        }
        cm += best;
        out_idx[(size_t)row * K + t] = (float)bi;

        if (t + 1 < K) {
            float rvbi = rvp[0];
#pragma unroll
            for (int p = 1; p < PP; p++) rvbi = (p == bi) ? rvp[p] : rvbi;
            rn2 = rn2 - 2.f * rvbi + vv_s[bi * PP + bi];
#pragma unroll
            for (int p = 0; p < PP; p++) { s[p] -= vk_s[bi * PP + p]; rvp[p] -= vv_s[bi * PP + p]; }
        }
    }
    cmrow[row] = cm;
}

// ---------------- kernel 4: wsum (original per-wave f64 sum order) ----------
__global__ __launch_bounds__(256) void pp_wsum(
    const float* __restrict__ cmrow, double* __restrict__ wsum, int B)
{
    const int g = blockIdx.x * 256 + threadIdx.x;   // 0..NWSUM-1
    if (g >= NWSUM) return;
    double s = 0.0;
    for (int r = g; r < B; r += NWSUM) s += (double)cmrow[r];  // same order as old csum
    wsum[g] = s;
}

// ---------------- kernel 5: broadcast writer (wave per (row,t) task) ---------
__global__ __launch_bounds__(256) void pp_bcast(
    const float* __restrict__ vals,
    const float* __restrict__ out_idx,
    float* __restrict__ out_sel,
    int nTask)
{
    const int lane = threadIdx.x & 63;
    const int wid  = blockIdx.x * 4 + (threadIdx.x >> 6);
    const int nw   = gridDim.x * 4;

    int task = wid;
    int bi = (task < nTask) ? (int)out_idx[task] : 0;
    while (task < nTask) {
        const int ntask = task + nw;
        const int nbi = (ntask < nTask) ? (int)out_idx[ntask] : 0;  // prefetch idx

        const float4* pv = (const float4*)(vals + (size_t)bi * D);
        float4* ob = (float4*)(out_sel + (size_t)task * D);
        float4 a = pv[lane], b = pv[lane + 64], c = pv[lane + 128], d = pv[lane + 192];
        ob[lane]       = a;
        ob[lane + 64]  = b;
        ob[lane + 128] = c;
        ob[lane + 192] = d;

        task = ntask; bi = nbi;
    }
}

// ---------------- kernel 6: loss reduce ----------------
__global__ __launch_bounds__(256) void pp_loss(
    const double* __restrict__ wsum, float* __restrict__ out_loss, int B)
{
    __shared__ double sh[4];
    const int tid = threadIdx.x;
    double s = 0.0;
    for (int i = tid; i < NWSUM; i += 256) s += wsum[i];
#pragma unroll
    for (int m = 1; m < 64; m <<= 1) s += __shfl_xor(s, m, 64);
    if ((tid & 63) == 0) sh[tid >> 6] = s;
    __syncthreads();
    if (tid == 0) {
        double tot = sh[0] + sh[1] + sh[2] + sh[3];
        out_loss[0] = (float)(-(tot / (double)B));
    }
}

extern "C" void kernel_launch(void* const* d_in, const int* in_sizes, int n_in,
                              void* d_out, int out_size, void* d_ws, size_t ws_size,
                              hipStream_t stream) {
    const float* input = (const float*)d_in[0];
    const float* keys  = (const float*)d_in[1];
    const float* vals  = (const float*)d_in[2];

    const int B = in_sizes[0] / D;                       // 32768
    const int K = (out_size - 1) / (B * (D + 1));        // 5

    float* out_sel  = (float*)d_out;
    const size_t selN = (size_t)B * K * D;
    float* out_loss = out_sel + selN;
    float* out_idx  = out_sel + selN + 1;

    char*  ws    = (char*)d_ws;
    float* nk    = (float*)ws;                           // PP*D f32 = 81920 B
    float* vkf   = nk + PP * D;                          // 400 f32
    float* vvf   = vkf + PP * PP;                        // 400 f32
    double* wsum = (double*)(ws + ((PP * D + 2 * PP * PP) * 4)); // 8-aligned

    // Large scratch lives INSIDE out_sel (regenerated in full by pp_bcast later):
    //   sbuf = [B][SBS] f32 (5.8 MB), cmrow = [B] f32 (128 KB) — far below selN.
    float* sbuf  = out_sel;
    float* cmrow = out_sel + (size_t)B * SBS;

    const int nTask = B * K;

    pp_pre1  <<<1, 1024, 0, stream>>>(keys, nk);
    pp_pre2  <<<(2 * PP * PP + 63) / 64, 64, 0, stream>>>(nk, vals, vkf, vvf);
    pp_dots  <<<NBK, TBK, 0, stream>>>(input, vals, nk, sbuf, B);
    pp_decide<<<(B + TDEC - 1) / TDEC, TDEC, 0, stream>>>(sbuf, vkf, vvf, out_idx, cmrow, B, K);
    pp_wsum  <<<(NWSUM + 255) / 256, 256, 0, stream>>>(cmrow, wsum, B);
    pp_bcast <<<2048, 256, 0, stream>>>(vals, out_idx, out_sel, nTask);
    pp_loss  <<<1, 256, 0, stream>>>(wsum, out_loss, B);
}